// Round 1
// 67.435 us; speedup vs baseline: 1.0072x; 1.0072x over previous
//
#include <hip/hip_runtime.h>

#define NN 2048
#define ROWS 32
#define TS 128                 // tile size
#define NT (NN / TS)           // 16 tiles per row
#define NPAIR (NT * (NT + 1) / 2)   // 136 tile-pairs (ta <= tb)
#define GRID (ROWS * NPAIR)    // 4352 blocks of 64 threads
#define THREADS 64

typedef float v4f __attribute__((ext_vector_type(4)));

// Each block: row r, tile pair (ta <= tb). Wave-wide counting:
// one v_cmp covers 64 (i,j) pairs; discordance mask = ballot(pj>pi) ^ ballot(qj>qi),
// counted on the SCALAR pipe (s_xor_b64 + s_bcnt1_b64 + s_add) which co-issues
// with VALU. 2 v_cmp per 64 pairs = 1.5x fewer VALU cycles than the packed-sub
// + alignbit scheme. disc is wave-uniform (SGPR) -> no shuffle-reduce tail.
// Off-diagonal blocks count each unordered cross pair once -> weight 2.
// Diagonal blocks count the full rect (self-pairs contribute 0) -> weight 1.
__global__ __launch_bounds__(THREADS) void ktau_count(const float* __restrict__ pred,
                                                      const float* __restrict__ target,
                                                      int* __restrict__ ws) {
    __shared__ v4f jtile[TS / 2];   // (p_j0, q_j0, p_j1, q_j1) -> ds_read_b128 = 2 j's

    const int blk = blockIdx.x;
    const int row = blk / NPAIR;
    int t = blk - row * NPAIR;
    // decode t -> (ta, tb), ta <= tb; row ta has (NT - ta) entries
    int ta = 0, base = 0;
    while (t >= base + (NT - ta)) { base += NT - ta; ++ta; }
    const int tb = ta + (t - base);

    const float* __restrict__ prow = pred   + row * NN;
    const float* __restrict__ qrow = target + row * NN;
    const int tid = threadIdx.x;

    // stage j-tile: 2 consecutive j per thread, interleaved p/q
    {
        const int j0 = tb * TS + tid * 2;
        float2 pj = *(const float2*)(prow + j0);
        float2 qj = *(const float2*)(qrow + j0);
        v4f v; v.x = pj.x; v.y = qj.x; v.z = pj.y; v.w = qj.y;
        jtile[tid] = v;
    }

    // i-side: 2 consecutive i per thread (8B-aligned float2 loads)
    const int i0 = ta * TS + tid * 2;
    float2 pp = *(const float2*)(prow + i0);
    float2 qq = *(const float2*)(qrow + i0);
    __syncthreads();

    unsigned disc = 0;
    #pragma unroll 8
    for (int jj = 0; jj < TS / 2; ++jj) {
        v4f j2 = jtile[jj];
        unsigned long long a, b;
        // j0 against both i's
        a = __ballot(j2.x > pp.x); b = __ballot(j2.y > qq.x);
        disc += (unsigned)__popcll(a ^ b);
        a = __ballot(j2.x > pp.y); b = __ballot(j2.y > qq.y);
        disc += (unsigned)__popcll(a ^ b);
        // j1 against both i's
        a = __ballot(j2.z > pp.x); b = __ballot(j2.w > qq.x);
        disc += (unsigned)__popcll(a ^ b);
        a = __ballot(j2.z > pp.y); b = __ballot(j2.w > qq.y);
        disc += (unsigned)__popcll(a ^ b);
    }

    // disc is wave-uniform: every lane computed the same scalar value.
    if (tid == 0)
        ws[blk] = (ta == tb) ? (int)disc : (int)(disc << 1);   // weighted
}

// Reduce GRID weighted partials. loss = (ordered discordant total) * invT / ROWS
__global__ __launch_bounds__(256) void ktau_final(const int* __restrict__ ws,
                                                  float* __restrict__ out) {
    __shared__ int wpart[4];
    const int tid = threadIdx.x;
    int v = 0;
    for (int b = tid; b < GRID; b += 256) v += ws[b];
    #pragma unroll
    for (int off = 32; off > 0; off >>= 1)
        v += __shfl_down(v, off, 64);
    if ((tid & 63) == 0) wpart[tid >> 6] = v;
    __syncthreads();
    if (tid == 0) {
        const float invT = 1.0f / (float)(((long long)NN * (NN - 1)) / 2);
        int total = wpart[0] + wpart[1] + wpart[2] + wpart[3];
        out[0] = (float)total * invT / (float)ROWS;
    }
}

extern "C" void kernel_launch(void* const* d_in, const int* in_sizes, int n_in,
                              void* d_out, int out_size, void* d_ws, size_t ws_size,
                              hipStream_t stream) {
    const float* pred   = (const float*)d_in[0];
    const float* target = (const float*)d_in[1];
    float* out = (float*)d_out;
    int* ws    = (int*)d_ws;

    ktau_count<<<GRID, THREADS, 0, stream>>>(pred, target, ws);
    ktau_final<<<1, 256, 0, stream>>>(ws, out);
}